// Round 1
// baseline (3524.106 us; speedup 1.0000x reference)
//
#include <hip/hip_runtime.h>

#define NN 50000
#define NE 1600000
#define NTOT (NE + NN)          // edges + self loops
#define IN_CH 128
#define HEADS 4
#define OUT_CH 32
#define HC 128                  // HEADS*OUT_CH
#define NEG_SLOPE 0.2f
#define EPS 1e-9f

// order-preserving float <-> uint encoding for atomicMax on signed floats
__device__ __forceinline__ unsigned int fenc(float f) {
    unsigned int u = __float_as_uint(f);
    return (u & 0x80000000u) ? ~u : (u | 0x80000000u);
}
__device__ __forceinline__ float fdec(unsigned int u) {
    return (u & 0x80000000u) ? __uint_as_float(u & 0x7fffffffu)
                             : __uint_as_float(~u);
}
// fenc(-inf) = ~0xFF800000 = 0x007FFFFF
#define ENC_NEG_INF 0x007FFFFFu

__device__ __forceinline__ void edge_src_dst(int e, const int* __restrict__ ei,
                                             int& src, int& dst) {
    if (e < NE) { src = ei[e]; dst = ei[NE + e]; }
    else        { src = e - NE; dst = src; }     // self loop
}

// ---------------------------------------------------------------- init ------
__global__ __launch_bounds__(256) void k_init(float* __restrict__ out,
                                              const float* __restrict__ bias,
                                              unsigned int* __restrict__ mx,
                                              float* __restrict__ denom) {
    int i = blockIdx.x * 256 + threadIdx.x;
    if (i < NN * HC) out[i] = bias[i & (HC - 1)];
    if (i < NN * HEADS) { mx[i] = ENC_NEG_INF; denom[i] = 0.0f; }
}

// ---------------------------------------------------- projection + logits ---
// one block (128 threads) per node; thread j computes h[n][j]
__global__ __launch_bounds__(128) void k_proj(const float* __restrict__ x,
                                              const float* __restrict__ W,
                                              const float* __restrict__ att_s,
                                              const float* __restrict__ att_d,
                                              float* __restrict__ h,
                                              float* __restrict__ a_s,
                                              float* __restrict__ a_d) {
    __shared__ float xs[IN_CH];
    const int n = blockIdx.x;
    const int j = threadIdx.x;
    xs[j] = x[n * IN_CH + j];
    __syncthreads();
    float acc = 0.0f;
#pragma unroll 8
    for (int k = 0; k < IN_CH; ++k)
        acc = fmaf(xs[k], W[k * HC + j], acc);
    h[n * HC + j] = acc;

    float ps = acc * att_s[j];
    float pd = acc * att_d[j];
#pragma unroll
    for (int m = 16; m >= 1; m >>= 1) {
        ps += __shfl_xor(ps, m, 64);
        pd += __shfl_xor(pd, m, 64);
    }
    if ((j & 31) == 0) {
        a_s[n * HEADS + (j >> 5)] = ps;
        a_d[n * HEADS + (j >> 5)] = pd;
    }
}

// ------------------------------------------------------------ segment max ---
__global__ __launch_bounds__(256) void k_edge_max(const int* __restrict__ ei,
                                                  const float* __restrict__ a_s,
                                                  const float* __restrict__ a_d,
                                                  unsigned int* __restrict__ mx) {
    int e = blockIdx.x * 256 + threadIdx.x;
    if (e >= NTOT) return;
    int src, dst;
    edge_src_dst(e, ei, src, dst);
    const float4 s4 = *(const float4*)(a_s + src * 4);
    const float4 d4 = *(const float4*)(a_d + dst * 4);
    float s[4] = {s4.x + d4.x, s4.y + d4.y, s4.z + d4.z, s4.w + d4.w};
#pragma unroll
    for (int hh = 0; hh < 4; ++hh) {
        float v = s[hh] >= 0.0f ? s[hh] : NEG_SLOPE * s[hh];
        atomicMax(&mx[dst * 4 + hh], fenc(v));
    }
}

// ----------------------------------------------------------- exp + denom ----
__global__ __launch_bounds__(256) void k_edge_exp(const int* __restrict__ ei,
                                                  const float* __restrict__ a_s,
                                                  const float* __restrict__ a_d,
                                                  const unsigned int* __restrict__ mx,
                                                  float* __restrict__ ex,
                                                  float* __restrict__ denom) {
    int e = blockIdx.x * 256 + threadIdx.x;
    if (e >= NTOT) return;
    int src, dst;
    edge_src_dst(e, ei, src, dst);
    const float4 s4 = *(const float4*)(a_s + src * 4);
    const float4 d4 = *(const float4*)(a_d + dst * 4);
    float s[4] = {s4.x + d4.x, s4.y + d4.y, s4.z + d4.z, s4.w + d4.w};
    float exh[4];
#pragma unroll
    for (int hh = 0; hh < 4; ++hh) {
        float v = s[hh] >= 0.0f ? s[hh] : NEG_SLOPE * s[hh];
        float m = fdec(mx[dst * 4 + hh]);
        exh[hh] = expf(v - m);
    }
    *(float4*)(ex + e * 4) = make_float4(exh[0], exh[1], exh[2], exh[3]);
#pragma unroll
    for (int hh = 0; hh < 4; ++hh)
        atomicAdd(&denom[dst * 4 + hh], exh[hh]);
}

// ------------------------------------------------------- weighted scatter ---
// 32 lanes per edge; lane handles 4 consecutive channels (float4)
__global__ __launch_bounds__(256) void k_scatter(const int* __restrict__ ei,
                                                 const float* __restrict__ h,
                                                 const float* __restrict__ ex,
                                                 const float* __restrict__ denom,
                                                 float* __restrict__ out) {
    int gid = blockIdx.x * 256 + threadIdx.x;
    int e = gid >> 5;
    int lane = gid & 31;
    if (e >= NTOT) return;
    int src, dst;
    edge_src_dst(e, ei, src, dst);
    const int head = lane >> 3;                     // (lane*4)/32
    const float alpha = ex[e * 4 + head] / (denom[dst * 4 + head] + EPS);
    const float4 hv = *(const float4*)(h + src * HC + lane * 4);
    float* o = out + dst * HC + lane * 4;
    atomicAdd(o + 0, alpha * hv.x);
    atomicAdd(o + 1, alpha * hv.y);
    atomicAdd(o + 2, alpha * hv.z);
    atomicAdd(o + 3, alpha * hv.w);
}

// ---------------------------------------------------------------------------
extern "C" void kernel_launch(void* const* d_in, const int* in_sizes, int n_in,
                              void* d_out, int out_size, void* d_ws, size_t ws_size,
                              hipStream_t stream) {
    const float* x     = (const float*)d_in[0];
    const int*   ei    = (const int*)d_in[1];
    const float* W     = (const float*)d_in[2];
    const float* att_s = (const float*)d_in[3];
    const float* att_d = (const float*)d_in[4];
    const float* bias  = (const float*)d_in[5];
    float* out = (float*)d_out;

    char* ws = (char*)d_ws;
    float*        h     = (float*)ws;          ws += (size_t)NN * HC * 4;       // 25.6 MB
    float*        a_s   = (float*)ws;          ws += (size_t)NN * HEADS * 4;    // 0.8 MB
    float*        a_d   = (float*)ws;          ws += (size_t)NN * HEADS * 4;    // 0.8 MB
    unsigned int* mx    = (unsigned int*)ws;   ws += (size_t)NN * HEADS * 4;    // 0.8 MB
    float*        denom = (float*)ws;          ws += (size_t)NN * HEADS * 4;    // 0.8 MB
    float*        ex    = (float*)ws;          ws += (size_t)NTOT * HEADS * 4;  // 26.4 MB

    k_init<<<(NN * HC + 255) / 256, 256, 0, stream>>>(out, bias, mx, denom);
    k_proj<<<NN, 128, 0, stream>>>(x, W, att_s, att_d, h, a_s, a_d);
    k_edge_max<<<(NTOT + 255) / 256, 256, 0, stream>>>(ei, a_s, a_d, mx);
    k_edge_exp<<<(NTOT + 255) / 256, 256, 0, stream>>>(ei, a_s, a_d, mx, ex, denom);
    k_scatter<<<((size_t)NTOT * 32 + 255) / 256, 256, 0, stream>>>(ei, h, ex, denom, out);
}

// Round 2
// 648.863 us; speedup vs baseline: 5.4312x; 5.4312x over previous
//
#include <hip/hip_runtime.h>

#define NN 50000
#define NE 1600000
#define IN_CH 128
#define HEADS 4
#define OUT_CH 32
#define HC 128                  // HEADS*OUT_CH
#define NEG_SLOPE 0.2f
#define EPS 1e-9f

__device__ __forceinline__ float leaky(float v) {
    return v >= 0.0f ? v : NEG_SLOPE * v;
}

// ---------------------------------------------------------------- init ------
__global__ __launch_bounds__(256) void k_init(int* __restrict__ deg) {
    int i = blockIdx.x * 256 + threadIdx.x;
    if (i < NN) deg[i] = 0;
}

// ---------------------------------------------------- projection + logits ---
// one block (128 threads) per node; thread j computes h[n][j]
__global__ __launch_bounds__(128) void k_proj(const float* __restrict__ x,
                                              const float* __restrict__ W,
                                              const float* __restrict__ att_s,
                                              const float* __restrict__ att_d,
                                              float* __restrict__ h,
                                              float* __restrict__ a_s,
                                              float* __restrict__ a_d) {
    __shared__ float xs[IN_CH];
    const int n = blockIdx.x;
    const int j = threadIdx.x;
    xs[j] = x[n * IN_CH + j];
    __syncthreads();
    float acc = 0.0f;
#pragma unroll 8
    for (int k = 0; k < IN_CH; ++k)
        acc = fmaf(xs[k], W[k * HC + j], acc);
    h[n * HC + j] = acc;

    float ps = acc * att_s[j];
    float pd = acc * att_d[j];
#pragma unroll
    for (int m = 16; m >= 1; m >>= 1) {
        ps += __shfl_xor(ps, m, 64);
        pd += __shfl_xor(pd, m, 64);
    }
    if ((j & 31) == 0) {
        a_s[n * HEADS + (j >> 5)] = ps;
        a_d[n * HEADS + (j >> 5)] = pd;
    }
}

// ------------------------------------------------------------ degree count --
__global__ __launch_bounds__(256) void k_count(const int* __restrict__ ei,
                                               int* __restrict__ deg) {
    int e = blockIdx.x * 256 + threadIdx.x;
    if (e < NE) atomicAdd(&deg[ei[NE + e]], 1);
}

// ------------------------------------------------------- exclusive scan -----
// single block, 1024 threads, chunk-per-thread + Hillis-Steele over partials
__global__ __launch_bounds__(1024) void k_scan(const int* __restrict__ deg,
                                               int* __restrict__ row_ptr,
                                               int* __restrict__ cursor) {
    __shared__ int part[1024];
    const int tid = threadIdx.x;
    const int CHUNK = (NN + 1023) / 1024;          // 49
    const int base = tid * CHUNK;
    int sum = 0;
    for (int i = 0; i < CHUNK; ++i) {
        int idx = base + i;
        if (idx < NN) sum += deg[idx];
    }
    part[tid] = sum;
    __syncthreads();
    for (int off = 1; off < 1024; off <<= 1) {
        int v = 0;
        if (tid >= off) v = part[tid - off];
        __syncthreads();
        if (tid >= off) part[tid] += v;
        __syncthreads();
    }
    int run = part[tid] - sum;                     // exclusive base of my chunk
    for (int i = 0; i < CHUNK; ++i) {
        int idx = base + i;
        if (idx < NN) {
            row_ptr[idx] = run;
            cursor[idx] = run;
            run += deg[idx];
        }
    }
}

// ------------------------------------------------------------- CSR fill -----
__global__ __launch_bounds__(256) void k_fill(const int* __restrict__ ei,
                                              int* __restrict__ cursor,
                                              int* __restrict__ csr_src) {
    int e = blockIdx.x * 256 + threadIdx.x;
    if (e >= NE) return;
    int src = ei[e];
    int dst = ei[NE + e];
    int pos = atomicAdd(&cursor[dst], 1);
    csr_src[pos] = src;
}

// ----------------------------------------------------- gather aggregation ---
// one wave (64 lanes) per dst node; lane owns channels 2*lane, 2*lane+1
__global__ __launch_bounds__(256) void k_agg(const int* __restrict__ row_ptr,
                                             const int* __restrict__ deg,
                                             const int* __restrict__ csr_src,
                                             const float* __restrict__ h,
                                             const float* __restrict__ a_s,
                                             const float* __restrict__ a_d,
                                             const float* __restrict__ bias,
                                             float* __restrict__ out) {
    const int n = blockIdx.x * 4 + (threadIdx.x >> 6);
    const int lane = threadIdx.x & 63;
    if (n >= NN) return;
    const int hd = lane >> 4;                      // head of my channel pair
    const int beg = row_ptr[n];
    const int end = beg + deg[n];

    const float4 ad4 = *(const float4*)(a_d + n * 4);
    const float4 asn4 = *(const float4*)(a_s + n * 4);

    // ---- pass 1: per-head max over self-loop + incoming edges -------------
    float4 mx4 = make_float4(leaky(asn4.x + ad4.x), leaky(asn4.y + ad4.y),
                             leaky(asn4.z + ad4.z), leaky(asn4.w + ad4.w));
    for (int i = beg + lane; i < end; i += 64) {
        int s = csr_src[i];
        const float4 as4 = *(const float4*)(a_s + s * 4);
        mx4.x = fmaxf(mx4.x, leaky(as4.x + ad4.x));
        mx4.y = fmaxf(mx4.y, leaky(as4.y + ad4.y));
        mx4.z = fmaxf(mx4.z, leaky(as4.z + ad4.z));
        mx4.w = fmaxf(mx4.w, leaky(as4.w + ad4.w));
    }
#pragma unroll
    for (int m = 32; m >= 1; m >>= 1) {
        mx4.x = fmaxf(mx4.x, __shfl_xor(mx4.x, m, 64));
        mx4.y = fmaxf(mx4.y, __shfl_xor(mx4.y, m, 64));
        mx4.z = fmaxf(mx4.z, __shfl_xor(mx4.z, m, 64));
        mx4.w = fmaxf(mx4.w, __shfl_xor(mx4.w, m, 64));
    }
    const float ad_h = hd == 0 ? ad4.x : hd == 1 ? ad4.y : hd == 2 ? ad4.z : ad4.w;
    const float mh   = hd == 0 ? mx4.x : hd == 1 ? mx4.y : hd == 2 ? mx4.z : mx4.w;
    const float as_h = hd == 0 ? asn4.x : hd == 1 ? asn4.y : hd == 2 ? asn4.z : asn4.w;

    // ---- pass 2: exp + weighted accumulate (division deferred) ------------
    float eself = __expf(leaky(as_h + ad_h) - mh);
    float denom = eself;
    const float2 hvself = *(const float2*)(h + (size_t)n * HC + 2 * lane);
    float acc0 = eself * hvself.x;
    float acc1 = eself * hvself.y;

    int s_next = (beg < end) ? csr_src[beg] : 0;
    for (int i = beg; i < end; ++i) {
        int s = s_next;
        if (i + 1 < end) s_next = csr_src[i + 1];
        float asv = a_s[s * 4 + hd];
        float ev = __expf(leaky(asv + ad_h) - mh);
        const float2 hv = *(const float2*)(h + (size_t)s * HC + 2 * lane);
        denom += ev;
        acc0 = fmaf(ev, hv.x, acc0);
        acc1 = fmaf(ev, hv.y, acc1);
    }
    const float inv = 1.0f / (denom + EPS);
    out[(size_t)n * HC + 2 * lane]     = acc0 * inv + bias[2 * lane];
    out[(size_t)n * HC + 2 * lane + 1] = acc1 * inv + bias[2 * lane + 1];
}

// ---------------------------------------------------------------------------
extern "C" void kernel_launch(void* const* d_in, const int* in_sizes, int n_in,
                              void* d_out, int out_size, void* d_ws, size_t ws_size,
                              hipStream_t stream) {
    const float* x     = (const float*)d_in[0];
    const int*   ei    = (const int*)d_in[1];
    const float* W     = (const float*)d_in[2];
    const float* att_s = (const float*)d_in[3];
    const float* att_d = (const float*)d_in[4];
    const float* bias  = (const float*)d_in[5];
    float* out = (float*)d_out;

    char* ws = (char*)d_ws;
    int*   deg     = (int*)ws;    ws += (size_t)NN * 4;
    int*   row_ptr = (int*)ws;    ws += (size_t)NN * 4;
    int*   cursor  = (int*)ws;    ws += (size_t)NN * 4;
    int*   csr_src = (int*)ws;    ws += (size_t)NE * 4;      // 6.4 MB
    float* h       = (float*)ws;  ws += (size_t)NN * HC * 4; // 25.6 MB
    float* a_s     = (float*)ws;  ws += (size_t)NN * HEADS * 4;
    float* a_d     = (float*)ws;  ws += (size_t)NN * HEADS * 4;

    k_init <<<(NN + 255) / 256, 256, 0, stream>>>(deg);
    k_proj <<<NN, 128, 0, stream>>>(x, W, att_s, att_d, h, a_s, a_d);
    k_count<<<(NE + 255) / 256, 256, 0, stream>>>(ei, deg);
    k_scan <<<1, 1024, 0, stream>>>(deg, row_ptr, cursor);
    k_fill <<<(NE + 255) / 256, 256, 0, stream>>>(ei, cursor, csr_src);
    k_agg  <<<(NN + 3) / 4, 256, 0, stream>>>(row_ptr, deg, csr_src, h, a_s, a_d, bias, out);
}

// Round 3
// 563.326 us; speedup vs baseline: 6.2559x; 1.1518x over previous
//
#include <hip/hip_runtime.h>

#define NN 50000
#define NE 1600000
#define IN_CH 128
#define HEADS 4
#define OUT_CH 32
#define HC 128                  // HEADS*OUT_CH
#define NEG_SLOPE 0.2f
#define EPS 1e-9f
#define NT 16                   // nodes per k_proj block (50000 = 16*3125)

__device__ __forceinline__ float leaky(float v) {
    return v >= 0.0f ? v : NEG_SLOPE * v;
}
__device__ __forceinline__ unsigned short f2bf(float f) {   // RNE bf16
    unsigned u = __float_as_uint(f);
    return (unsigned short)((u + 0x7fffu + ((u >> 16) & 1u)) >> 16);
}
__device__ __forceinline__ float bf2f(unsigned short b) {
    return __uint_as_float((unsigned)b << 16);
}

// ---------------------------------------------------------------- init ------
__global__ __launch_bounds__(256) void k_init(int* __restrict__ deg) {
    int i = blockIdx.x * 256 + threadIdx.x;
    if (i < NN) deg[i] = 0;
}

// ---------------------------------------------------- projection + logits ---
// 128 threads, NT nodes per block; thread j owns output channel j
__global__ __launch_bounds__(128) void k_proj(const float* __restrict__ x,
                                              const float* __restrict__ W,
                                              const float* __restrict__ att_s,
                                              const float* __restrict__ att_d,
                                              unsigned short* __restrict__ h_bf,
                                              float* __restrict__ a_s,
                                              float* __restrict__ a_d) {
    __shared__ float xs[NT][IN_CH];
    const int j = threadIdx.x;
    const int n0 = blockIdx.x * NT;
#pragma unroll
    for (int t = 0; t < NT; ++t)
        xs[t][j] = x[(size_t)(n0 + t) * IN_CH + j];
    __syncthreads();

    float acc[NT];
#pragma unroll
    for (int t = 0; t < NT; ++t) acc[t] = 0.0f;
    for (int k = 0; k < IN_CH; ++k) {
        const float wk = W[k * HC + j];
#pragma unroll
        for (int t = 0; t < NT; ++t)
            acc[t] = fmaf(xs[t][k], wk, acc[t]);
    }

    const float asj = att_s[j];
    const float adj = att_d[j];
#pragma unroll
    for (int t = 0; t < NT; ++t) {
        h_bf[(size_t)(n0 + t) * HC + j] = f2bf(acc[t]);
        float ps = acc[t] * asj;
        float pd = acc[t] * adj;
#pragma unroll
        for (int m = 16; m >= 1; m >>= 1) {
            ps += __shfl_xor(ps, m, 64);
            pd += __shfl_xor(pd, m, 64);
        }
        if ((j & 31) == 0) {
            a_s[(n0 + t) * HEADS + (j >> 5)] = ps;
            a_d[(n0 + t) * HEADS + (j >> 5)] = pd;
        }
    }
}

// ------------------------------------------------------------ degree count --
__global__ __launch_bounds__(256) void k_count(const int* __restrict__ ei,
                                               int* __restrict__ deg) {
    int e = blockIdx.x * 256 + threadIdx.x;
    if (e < NE) atomicAdd(&deg[ei[NE + e]], 1);
}

// ------------------------------------------------------- exclusive scan -----
__global__ __launch_bounds__(1024) void k_scan(const int* __restrict__ deg,
                                               int* __restrict__ row_ptr,
                                               int* __restrict__ cursor) {
    __shared__ int part[1024];
    const int tid = threadIdx.x;
    const int CHUNK = (NN + 1023) / 1024;          // 49
    const int base = tid * CHUNK;
    int sum = 0;
    for (int i = 0; i < CHUNK; ++i) {
        int idx = base + i;
        if (idx < NN) sum += deg[idx];
    }
    part[tid] = sum;
    __syncthreads();
    for (int off = 1; off < 1024; off <<= 1) {
        int v = 0;
        if (tid >= off) v = part[tid - off];
        __syncthreads();
        if (tid >= off) part[tid] += v;
        __syncthreads();
    }
    int run = part[tid] - sum;
    for (int i = 0; i < CHUNK; ++i) {
        int idx = base + i;
        if (idx < NN) {
            row_ptr[idx] = run;
            cursor[idx] = run;
            run += deg[idx];
        }
    }
}

// ------------------------------------------------------------- CSR fill -----
__global__ __launch_bounds__(256) void k_fill(const int* __restrict__ ei,
                                              int* __restrict__ cursor,
                                              int* __restrict__ csr_src) {
    int e = blockIdx.x * 256 + threadIdx.x;
    if (e >= NE) return;
    int src = ei[e];
    int dst = ei[NE + e];
    int pos = atomicAdd(&cursor[dst], 1);
    csr_src[pos] = src;
}

// ----------------------------------------------------- gather aggregation ---
// one wave per dst node; lane owns channels 2*lane, 2*lane+1
__global__ __launch_bounds__(256) void k_agg(const int* __restrict__ row_ptr,
                                             const int* __restrict__ deg,
                                             const int* __restrict__ csr_src,
                                             const unsigned short* __restrict__ h_bf,
                                             const float* __restrict__ a_s,
                                             const float* __restrict__ a_d,
                                             const float* __restrict__ bias,
                                             float* __restrict__ out) {
    const int n = blockIdx.x * 4 + (threadIdx.x >> 6);
    const int lane = threadIdx.x & 63;
    if (n >= NN) return;
    const int hd = lane >> 4;
    const int beg = row_ptr[n];
    const int end = beg + deg[n];

    const float4 ad4 = *(const float4*)(a_d + n * 4);
    const float4 asn4 = *(const float4*)(a_s + n * 4);

    // ---- pass 1: per-head max (self-loop + incoming) ----------------------
    float4 mx4 = make_float4(leaky(asn4.x + ad4.x), leaky(asn4.y + ad4.y),
                             leaky(asn4.z + ad4.z), leaky(asn4.w + ad4.w));
    for (int i = beg + lane; i < end; i += 64) {
        int s = csr_src[i];
        const float4 as4 = *(const float4*)(a_s + s * 4);
        mx4.x = fmaxf(mx4.x, leaky(as4.x + ad4.x));
        mx4.y = fmaxf(mx4.y, leaky(as4.y + ad4.y));
        mx4.z = fmaxf(mx4.z, leaky(as4.z + ad4.z));
        mx4.w = fmaxf(mx4.w, leaky(as4.w + ad4.w));
    }
#pragma unroll
    for (int m = 32; m >= 1; m >>= 1) {
        mx4.x = fmaxf(mx4.x, __shfl_xor(mx4.x, m, 64));
        mx4.y = fmaxf(mx4.y, __shfl_xor(mx4.y, m, 64));
        mx4.z = fmaxf(mx4.z, __shfl_xor(mx4.z, m, 64));
        mx4.w = fmaxf(mx4.w, __shfl_xor(mx4.w, m, 64));
    }
    const float ad_h = hd == 0 ? ad4.x : hd == 1 ? ad4.y : hd == 2 ? ad4.z : ad4.w;
    const float mh   = hd == 0 ? mx4.x : hd == 1 ? mx4.y : hd == 2 ? mx4.z : mx4.w;
    const float as_h = hd == 0 ? asn4.x : hd == 1 ? asn4.y : hd == 2 ? asn4.z : asn4.w;

    // ---- pass 2: exp + weighted accumulate (division deferred) ------------
    float eself = __expf(leaky(as_h + ad_h) - mh);
    float denom = eself;
    const ushort2 hs = *(const ushort2*)(h_bf + (size_t)n * HC + 2 * lane);
    float acc0 = eself * bf2f(hs.x);
    float acc1 = eself * bf2f(hs.y);

    int s_next = (beg < end) ? csr_src[beg] : 0;
    for (int i = beg; i < end; ++i) {
        int s = s_next;
        if (i + 1 < end) s_next = csr_src[i + 1];
        float asv = a_s[s * 4 + hd];
        float ev = __expf(leaky(asv + ad_h) - mh);
        const ushort2 hv = *(const ushort2*)(h_bf + (size_t)s * HC + 2 * lane);
        denom += ev;
        acc0 = fmaf(ev, bf2f(hv.x), acc0);
        acc1 = fmaf(ev, bf2f(hv.y), acc1);
    }
    const float inv = 1.0f / (denom + EPS);
    out[(size_t)n * HC + 2 * lane]     = acc0 * inv + bias[2 * lane];
    out[(size_t)n * HC + 2 * lane + 1] = acc1 * inv + bias[2 * lane + 1];
}

// ---------------------------------------------------------------------------
extern "C" void kernel_launch(void* const* d_in, const int* in_sizes, int n_in,
                              void* d_out, int out_size, void* d_ws, size_t ws_size,
                              hipStream_t stream) {
    const float* x     = (const float*)d_in[0];
    const int*   ei    = (const int*)d_in[1];
    const float* W     = (const float*)d_in[2];
    const float* att_s = (const float*)d_in[3];
    const float* att_d = (const float*)d_in[4];
    const float* bias  = (const float*)d_in[5];
    float* out = (float*)d_out;

    char* ws = (char*)d_ws;
    int*   deg     = (int*)ws;    ws += (size_t)NN * 4;
    int*   row_ptr = (int*)ws;    ws += (size_t)NN * 4;
    int*   cursor  = (int*)ws;    ws += (size_t)NN * 4;
    int*   csr_src = (int*)ws;    ws += (size_t)NE * 4;          // 6.4 MB
    unsigned short* h_bf = (unsigned short*)ws; ws += (size_t)NN * HC * 2; // 12.8 MB
    float* a_s     = (float*)ws;  ws += (size_t)NN * HEADS * 4;
    float* a_d     = (float*)ws;  ws += (size_t)NN * HEADS * 4;

    k_init <<<(NN + 255) / 256, 256, 0, stream>>>(deg);
    k_proj <<<NN / NT, 128, 0, stream>>>(x, W, att_s, att_d, h_bf, a_s, a_d);
    k_count<<<(NE + 255) / 256, 256, 0, stream>>>(ei, deg);
    k_scan <<<1, 1024, 0, stream>>>(deg, row_ptr, cursor);
    k_fill <<<(NE + 255) / 256, 256, 0, stream>>>(ei, cursor, csr_src);
    k_agg  <<<(NN + 3) / 4, 256, 0, stream>>>(row_ptr, deg, csr_src, h_bf, a_s, a_d, bias, out);
}